// Round 7
// baseline (147.685 us; speedup 1.0000x reference)
//
#include <hip/hip_runtime.h>
#include <hip/hip_bf16.h>

#define N_ROWS 4096
#define TWO_N 8192
#define DIM 512
#define BK 32
#define NKS (DIM / BK)                      // 16 K-steps
#define INV_T 14.285714285714286f           // 1/0.07
#define LOG2E 1.4426950408889634f
#define C_LOG2E 20.60992915555662f          // (1/0.07)*log2(e)
#define INV_SQRT_T 3.7796447300922722f      // 1/sqrt(0.07)

typedef __bf16 bf16x8 __attribute__((ext_vector_type(8)));
typedef float f32x4 __attribute__((ext_vector_type(4)));

#define ASYNC_COPY16(gp, lp)                                                     \
  __builtin_amdgcn_global_load_lds((const __attribute__((address_space(1))) void*)(gp), \
                                   (__attribute__((address_space(3))) void*)(lp), 16, 0, 0)

#define VMCNT(n) asm volatile("s_waitcnt vmcnt(" #n ")" ::: "memory")

// Wave-per-row prep: float4 loads, butterfly shuffle reduce (no LDS/sync),
// 16B bf16x8 stores. 1024 blocks x 4 waves = 4096 rows; also zeroes rowsum.
__global__ __launch_bounds__(256) void k_prep(const float* __restrict__ z1,
                                              const float* __restrict__ z2,
                                              __hip_bfloat16* __restrict__ zn,
                                              float* __restrict__ posbuf,
                                              float* __restrict__ rowsum) {
  const int t = threadIdx.x;
  const int wv = t >> 6, lane = t & 63;
  const int r = blockIdx.x * 4 + wv;
  if (blockIdx.x < 32) rowsum[blockIdx.x * 256 + t] = 0.f;   // 32*256 = 8192

  const float4* p1 = reinterpret_cast<const float4*>(z1 + (size_t)r * DIM) + (lane << 1);
  const float4* p2 = reinterpret_cast<const float4*>(z2 + (size_t)r * DIM) + (lane << 1);
  float4 a0 = p1[0], a1 = p1[1];
  float4 b0 = p2[0], b1 = p2[1];

  float s1 = a0.x * a0.x + a0.y * a0.y + a0.z * a0.z + a0.w * a0.w
           + a1.x * a1.x + a1.y * a1.y + a1.z * a1.z + a1.w * a1.w;
  float s2 = b0.x * b0.x + b0.y * b0.y + b0.z * b0.z + b0.w * b0.w
           + b1.x * b1.x + b1.y * b1.y + b1.z * b1.z + b1.w * b1.w;
  float sd = a0.x * b0.x + a0.y * b0.y + a0.z * b0.z + a0.w * b0.w
           + a1.x * b1.x + a1.y * b1.y + a1.z * b1.z + a1.w * b1.w;
#pragma unroll
  for (int off = 1; off < 64; off <<= 1) {
    s1 += __shfl_xor(s1, off, 64);
    s2 += __shfl_xor(s2, off, 64);
    sd += __shfl_xor(sd, off, 64);
  }
  const float sc1 = INV_SQRT_T / fmaxf(sqrtf(s1), 1e-8f);
  const float sc2 = INV_SQRT_T / fmaxf(sqrtf(s2), 1e-8f);

  bf16x8 o;
  o[0] = (__bf16)(a0.x * sc1); o[1] = (__bf16)(a0.y * sc1);
  o[2] = (__bf16)(a0.z * sc1); o[3] = (__bf16)(a0.w * sc1);
  o[4] = (__bf16)(a1.x * sc1); o[5] = (__bf16)(a1.y * sc1);
  o[6] = (__bf16)(a1.z * sc1); o[7] = (__bf16)(a1.w * sc1);
  *reinterpret_cast<bf16x8*>(zn + (size_t)r * DIM + (lane << 3)) = o;

  o[0] = (__bf16)(b0.x * sc2); o[1] = (__bf16)(b0.y * sc2);
  o[2] = (__bf16)(b0.z * sc2); o[3] = (__bf16)(b0.w * sc2);
  o[4] = (__bf16)(b1.x * sc2); o[5] = (__bf16)(b1.y * sc2);
  o[6] = (__bf16)(b1.z * sc2); o[7] = (__bf16)(b1.w * sc2);
  *reinterpret_cast<bf16x8*>(zn + (size_t)(r + N_ROWS) * DIM + (lane << 3)) = o;

  if (lane == 0) posbuf[r] = sd * sc1 * sc2;   // = cos(z1_r,z2_r)/T
}

// ---------------------------------------------------------------------------
// Flash-LSE GEMM over upper-triangle 128x128 tiles.
// REGISTER-FRAGMENT DOUBLE BUFFER on top of r2's counted-vmcnt skeleton.
// During iter ks we prefetch the fragments of ks+1 from LDS into a second
// register set, so the 16 MFMA of iter ks issue IMMEDIATELY at barrier
// release (operands were ds_read a full iteration ago; the new ds_reads and
// stage loads fly UNDER the MFMA cluster instead of in front of it). This
// attacks the measured ~1246cy/iter serial chain (barrier -> 8 ds_read
// latency ~400-600cy -> 310cy MFMA -> barrier) that left every pipe <40%.
// Needs buf[ks+1] resident one iter early -> 4 LDS buffers (64 KB, 2
// blocks/CU), stages 3 deep, VMCNT(4) waits on 2-iteration-old loads.
//   iter ks: VMCNT(4)[stage ks+1 landed] ; barrier ;
//            STAGE(ks+3) ; LOADFRAGS(ks+1) ; 16x MFMA(frags ks)
// Safety: STAGE(ks+3) overwrites buf[(ks+3)&3] = buf[(ks-1)&3], whose
// fragment reads (issued iter ks-2) completed before iter ks-1's MFMA
// (register dependency) on every wave, and all waves passed this iter's
// barrier -- so no wave can still be reading it.
//
// LDS swizzle (r4-proven, 0 bank conflicts): granule of logical (row,g)
// stored at slot row*4 + (g ^ ((row>>1)&3)); store side keeps LDS dest
// linear and pre-swizzles the GLOBAL source granule (rule #21); ds_read
// applies the same XOR (kxl).
// ---------------------------------------------------------------------------
__global__ __launch_bounds__(256, 2) void k_lse(const __hip_bfloat16* __restrict__ Zn,
                                                float* __restrict__ rowsum) {
  __shared__ char smem[65536] __attribute__((aligned(16)));
  const int tid  = threadIdx.x;
  const int wave = tid >> 6;
  const int lane = tid & 63;
  const int cl   = lane & 15;
  const int q    = lane >> 4;

  // XCD-aware bijective swizzle: 2080 = 8 * 260.
  const int b = (blockIdx.x & 7) * 260 + (blockIdx.x >> 3);

  // linear tile -> (rt, ct) with rt <= ct over 64x64 tile grid
  int rt = (int)((129.0f - sqrtf(16641.0f - 8.0f * (float)b)) * 0.5f);
  if (rt > 63) rt = 63;
  if (rt < 0) rt = 0;
  while (rt > 0 && 64 * rt - rt * (rt - 1) / 2 > b) rt--;
  while (64 * (rt + 1) - (rt + 1) * rt / 2 <= b) rt++;
  const int ct = rt + (b - (64 * rt - rt * (rt - 1) / 2));

  const int wr = (wave >> 1) * 64;   // wave's row offset in tile
  const int wc = (wave & 1) * 64;    // wave's col offset in tile

  // staging: thread owns slots tid, tid+256 of each 128x32 tile (512 granules)
  const int r0  = tid >> 2;                         // 0..63
  const int kg0 = (tid & 3) ^ ((tid >> 3) & 3);     // pre-swizzled granule
  const __hip_bfloat16* gA0 = Zn + (size_t)(rt * 128 + r0) * DIM + kg0 * 8;
  const __hip_bfloat16* gB0 = Zn + (size_t)(ct * 128 + r0) * DIM + kg0 * 8;

  f32x4 acc[4][4] = {};
  // fragment-read byte offset within a row: same XOR as the store side
  const int kxl = (q ^ ((cl >> 1) & 3)) << 4;

#define STAGE(d, ks1)                                                       \
  {                                                                         \
    char* _b = smem + (d) * 16384 + wave * 1024;                            \
    const int _ko = (ks1) * BK;                                             \
    ASYNC_COPY16(gA0 + _ko,            _b);                                 \
    ASYNC_COPY16(gA0 + _ko + 64 * DIM, _b + 4096);                          \
    ASYNC_COPY16(gB0 + _ko,            _b + 8192);                          \
    ASYNC_COPY16(gB0 + _ko + 64 * DIM, _b + 12288);                         \
  }

  bf16x8 fra[2][4], frb[2][4];
#define LOADFRAGS(p, d)                                                     \
  {                                                                         \
    const char* _sA = smem + (d) * 16384;                                   \
    const char* _sB = _sA + 8192;                                           \
    _Pragma("unroll") for (int i = 0; i < 4; i++)                           \
      fra[p][i] = *reinterpret_cast<const bf16x8*>(_sA + (wr + i * 16 + cl) * 64 + kxl); \
    _Pragma("unroll") for (int j = 0; j < 4; j++)                           \
      frb[p][j] = *reinterpret_cast<const bf16x8*>(_sB + (wc + j * 16 + cl) * 64 + kxl); \
  }

  // prologue: 3 K-steps staged; buf0 drained; frags(0) prefetched.
  STAGE(0, 0);
  STAGE(1, 1);
  STAGE(2, 2);
  VMCNT(8);
  __builtin_amdgcn_s_barrier();
  LOADFRAGS(0, 0);

#pragma unroll
  for (int ks = 0; ks < NKS; ks++) {
    // in-flight at entry: stages for steps ks+1 (older) and ks+2 (newer).
    // VMCNT(4) -> the older stage (buf[(ks+1)&3]) has landed.
    if (ks + 2 < NKS) { VMCNT(4); } else { VMCNT(0); }
    __builtin_amdgcn_s_barrier();
    if (ks + 3 < NKS) STAGE((ks + 3) & 3, ks + 3);
    if (ks + 1 < NKS) LOADFRAGS((ks + 1) & 1, (ks + 1) & 3);
    const int p = ks & 1;
#pragma unroll
    for (int i = 0; i < 4; i++)
#pragma unroll
      for (int j = 0; j < 4; j++)
        acc[i][j] = __builtin_amdgcn_mfma_f32_16x16x32_bf16(fra[p][i], frb[p][j],
                                                            acc[i][j], 0, 0, 0);
  }
#undef STAGE
#undef LOADFRAGS

  // Epilogue: e = exp(s - C) with diagonal masked.
  // C-frag layout: col = cl, row = q*4 + r (within 16x16 frag (i,j)).
  const bool diagw = (rt == ct) && (wr == wc);
  float psum[4][4];
#pragma unroll
  for (int i = 0; i < 4; i++)
#pragma unroll
    for (int r = 0; r < 4; r++) psum[i][r] = 0.f;
  float colp[4] = {0.f, 0.f, 0.f, 0.f};

#pragma unroll
  for (int i = 0; i < 4; i++)
#pragma unroll
    for (int j = 0; j < 4; j++)
#pragma unroll
      for (int r = 0; r < 4; r++) {
        float e = exp2f(fmaf(acc[i][j][r], LOG2E, -C_LOG2E));
        if (diagw && (i == j) && (cl == q * 4 + r)) e = 0.f;
        psum[i][r] += e;
        colp[j] += e;
      }

  // row sums -> rt rows (reduce across cols: cl lanes)
#pragma unroll
  for (int i = 0; i < 4; i++)
#pragma unroll
    for (int r = 0; r < 4; r++) {
      float v = psum[i][r];
      v += __shfl_xor(v, 1, 64);
      v += __shfl_xor(v, 2, 64);
      v += __shfl_xor(v, 4, 64);
      v += __shfl_xor(v, 8, 64);
      if (cl == 0) atomicAdd(&rowsum[rt * 128 + wr + i * 16 + q * 4 + r], v);
    }

  // col sums -> ct rows (reduce across rows: q lanes), off-diagonal tiles only
  if (rt != ct) {
#pragma unroll
    for (int j = 0; j < 4; j++) {
      float v = colp[j];
      v += __shfl_xor(v, 16, 64);
      v += __shfl_xor(v, 32, 64);
      if (q == 0) atomicAdd(&rowsum[ct * 128 + wc + j * 16 + cl], v);
    }
  }
}

// Single-block finalize: 1024 threads, each handles 8 rows.
__global__ void k_final(const float* __restrict__ rowsum, const float* __restrict__ posbuf,
                        float* __restrict__ out) {
  __shared__ float red[16];
  const int t = threadIdx.x;   // 1024 threads
  float s = 0.f;
#pragma unroll
  for (int it = 0; it < TWO_N / 1024; it++) {
    const int row = it * 1024 + t;
    float v = logf(rowsum[row]);
    if (row < N_ROWS) v -= 2.f * posbuf[row];
    s += v;
  }
#pragma unroll
  for (int off = 32; off > 0; off >>= 1) s += __shfl_down(s, off, 64);
  if ((t & 63) == 0) red[t >> 6] = s;
  __syncthreads();
  if (t == 0) {
    float tot = 0.f;
#pragma unroll
    for (int i = 0; i < 16; i++) tot += red[i];
    out[0] = tot / (float)TWO_N + INV_T;
  }
}

extern "C" void kernel_launch(void* const* d_in, const int* in_sizes, int n_in,
                              void* d_out, int out_size, void* d_ws, size_t ws_size,
                              hipStream_t stream) {
  const float* z1 = (const float*)d_in[0];
  const float* z2 = (const float*)d_in[1];
  float* out = (float*)d_out;
  char* ws = (char*)d_ws;

  __hip_bfloat16* zn = (__hip_bfloat16*)ws;              // 8192*512*2 = 8388608 B
  float* rowsum = (float*)(ws + 8388608);                 // 8192*4 = 32768 B
  float* posbuf = (float*)(ws + 8421376);                 // 4096*4 = 16384 B

  k_prep<<<1024, 256, 0, stream>>>(z1, z2, zn, posbuf, rowsum);
  k_lse<<<2080, 256, 0, stream>>>(zn, rowsum);
  k_final<<<1, 1024, 0, stream>>>(rowsum, posbuf, out);
}

// Round 8
// 133.268 us; speedup vs baseline: 1.1082x; 1.1082x over previous
//
#include <hip/hip_runtime.h>
#include <hip/hip_bf16.h>

#define N_ROWS 4096
#define TWO_N 8192
#define DIM 512
#define BK 32
#define NKS (DIM / BK)                      // 16 K-steps
#define INV_T 14.285714285714286f           // 1/0.07
#define LOG2E 1.4426950408889634f
#define C_LOG2E 20.60992915555662f          // (1/0.07)*log2(e)
#define INV_SQRT_T 3.7796447300922722f      // 1/sqrt(0.07)

typedef __bf16 bf16x8 __attribute__((ext_vector_type(8)));
typedef float f32x4 __attribute__((ext_vector_type(4)));

#define ASYNC_COPY16(gp, lp)                                                     \
  __builtin_amdgcn_global_load_lds((const __attribute__((address_space(1))) void*)(gp), \
                                   (__attribute__((address_space(3))) void*)(lp), 16, 0, 0)

#define VMCNT(n) asm volatile("s_waitcnt vmcnt(" #n ")" ::: "memory")

// Wave-per-row prep: float4 loads, butterfly shuffle reduce (no LDS/sync),
// 16B bf16x8 stores. 1024 blocks x 4 waves = 4096 rows; also zeroes rowsum.
__global__ __launch_bounds__(256) void k_prep(const float* __restrict__ z1,
                                              const float* __restrict__ z2,
                                              __hip_bfloat16* __restrict__ zn,
                                              float* __restrict__ posbuf,
                                              float* __restrict__ rowsum) {
  const int t = threadIdx.x;
  const int wv = t >> 6, lane = t & 63;
  const int r = blockIdx.x * 4 + wv;
  if (blockIdx.x < 32) rowsum[blockIdx.x * 256 + t] = 0.f;   // 32*256 = 8192

  const float4* p1 = reinterpret_cast<const float4*>(z1 + (size_t)r * DIM) + (lane << 1);
  const float4* p2 = reinterpret_cast<const float4*>(z2 + (size_t)r * DIM) + (lane << 1);
  float4 a0 = p1[0], a1 = p1[1];
  float4 b0 = p2[0], b1 = p2[1];

  float s1 = a0.x * a0.x + a0.y * a0.y + a0.z * a0.z + a0.w * a0.w
           + a1.x * a1.x + a1.y * a1.y + a1.z * a1.z + a1.w * a1.w;
  float s2 = b0.x * b0.x + b0.y * b0.y + b0.z * b0.z + b0.w * b0.w
           + b1.x * b1.x + b1.y * b1.y + b1.z * b1.z + b1.w * b1.w;
  float sd = a0.x * b0.x + a0.y * b0.y + a0.z * b0.z + a0.w * b0.w
           + a1.x * b1.x + a1.y * b1.y + a1.z * b1.z + a1.w * b1.w;
#pragma unroll
  for (int off = 1; off < 64; off <<= 1) {
    s1 += __shfl_xor(s1, off, 64);
    s2 += __shfl_xor(s2, off, 64);
    sd += __shfl_xor(sd, off, 64);
  }
  const float sc1 = INV_SQRT_T / fmaxf(sqrtf(s1), 1e-8f);
  const float sc2 = INV_SQRT_T / fmaxf(sqrtf(s2), 1e-8f);

  bf16x8 o;
  o[0] = (__bf16)(a0.x * sc1); o[1] = (__bf16)(a0.y * sc1);
  o[2] = (__bf16)(a0.z * sc1); o[3] = (__bf16)(a0.w * sc1);
  o[4] = (__bf16)(a1.x * sc1); o[5] = (__bf16)(a1.y * sc1);
  o[6] = (__bf16)(a1.z * sc1); o[7] = (__bf16)(a1.w * sc1);
  *reinterpret_cast<bf16x8*>(zn + (size_t)r * DIM + (lane << 3)) = o;

  o[0] = (__bf16)(b0.x * sc2); o[1] = (__bf16)(b0.y * sc2);
  o[2] = (__bf16)(b0.z * sc2); o[3] = (__bf16)(b0.w * sc2);
  o[4] = (__bf16)(b1.x * sc2); o[5] = (__bf16)(b1.y * sc2);
  o[6] = (__bf16)(b1.z * sc2); o[7] = (__bf16)(b1.w * sc2);
  *reinterpret_cast<bf16x8*>(zn + (size_t)(r + N_ROWS) * DIM + (lane << 3)) = o;

  if (lane == 0) posbuf[r] = sd * sc1 * sc2;   // = cos(z1_r,z2_r)/T
}

// ---------------------------------------------------------------------------
// Flash-LSE GEMM over upper-triangle 128x128 tiles.
// CHAMPION SKELETON (r2, 67.5us): 3 LDS buffers (48KB -> 3 blocks/CU), raw
// s_barrier with COUNTED VMCNT(4) (2-iteration load slack, full drain only
// at the tail), stage issued after the barrier, XCD-bijective block swizzle.
// THIS ROUND'S ONLY CHANGE: replace the rotation LDS swizzle (which leaked
// 4.26M bank-conflict cycles/dispatch ~ +128cy per iter on the serial
// LDS-read path) with the XOR swizzle proven conflict-FREE in r4/r5/r7.
//
// XOR swizzle (rule #21, both sides): 16B granule of logical (row,g) stored
// at slot row*4 + (g ^ ((row>>1)&3)). The LDS dest stays linear (slot=tid,
// global_load_lds scatters lane*16); the GLOBAL source granule is
// pre-swizzled kg0 = (tid&3)^((tid>>3)&3); fragment reads apply the same
// XOR via kxl = (q ^ ((cl>>1)&3))<<4 -> each 16-lane batch covers all 8
// bank quads, 2 lanes each (2-way aliasing is free).
//
// Schedule per iter ks (buffers mod 3):
//   VMCNT(4)            -- stage(ks) [issued at ks-2] has landed
//   s_barrier
//   STAGE(ks+2)         -- safe: all waves passed barrier, buf last read ks-1
//   8x ds_read_b128 (conflict-free) ; 16x MFMA
// ---------------------------------------------------------------------------
__global__ __launch_bounds__(256, 3) void k_lse(const __hip_bfloat16* __restrict__ Zn,
                                                float* __restrict__ rowsum) {
  __shared__ char smem[49152] __attribute__((aligned(16)));
  const int tid  = threadIdx.x;
  const int wave = tid >> 6;
  const int lane = tid & 63;
  const int cl   = lane & 15;
  const int q    = lane >> 4;

  // XCD-aware bijective swizzle: 2080 = 8 * 260.
  const int b = (blockIdx.x & 7) * 260 + (blockIdx.x >> 3);

  // linear tile -> (rt, ct) with rt <= ct over 64x64 tile grid
  int rt = (int)((129.0f - sqrtf(16641.0f - 8.0f * (float)b)) * 0.5f);
  if (rt > 63) rt = 63;
  if (rt < 0) rt = 0;
  while (rt > 0 && 64 * rt - rt * (rt - 1) / 2 > b) rt--;
  while (64 * (rt + 1) - (rt + 1) * rt / 2 <= b) rt++;
  const int ct = rt + (b - (64 * rt - rt * (rt - 1) / 2));

  const int wr = (wave >> 1) * 64;   // wave's row offset in tile
  const int wc = (wave & 1) * 64;    // wave's col offset in tile

  // staging: thread owns slots tid, tid+256 of each 128x32 tile (512 granules)
  const int r0  = tid >> 2;                         // 0..63
  const int kg0 = (tid & 3) ^ ((tid >> 3) & 3);     // pre-swizzled granule
  const __hip_bfloat16* gA0 = Zn + (size_t)(rt * 128 + r0) * DIM + kg0 * 8;
  const __hip_bfloat16* gB0 = Zn + (size_t)(ct * 128 + r0) * DIM + kg0 * 8;

  f32x4 acc[4][4] = {};
  // fragment-read byte offset within a row: same XOR as the store side
  const int kxl = (q ^ ((cl >> 1) & 3)) << 4;

#define STAGE(d, ks1)                                                       \
  {                                                                         \
    char* _b = smem + (d) * 16384 + wave * 1024;                            \
    const int _ko = (ks1) * BK;                                             \
    ASYNC_COPY16(gA0 + _ko,            _b);                                 \
    ASYNC_COPY16(gA0 + _ko + 64 * DIM, _b + 4096);                          \
    ASYNC_COPY16(gB0 + _ko,            _b + 8192);                          \
    ASYNC_COPY16(gB0 + _ko + 64 * DIM, _b + 12288);                         \
  }

  STAGE(0, 0);
  STAGE(1, 1);
#pragma unroll
  for (int ks = 0; ks < NKS; ks++) {
    const int cur = ks % 3;
    // wait for buf[cur]'s 4 loads (issued 2 iterations ago); the newest 4
    // (next buffer) stay in flight. Full drain only on the last iteration.
    if (ks + 1 < NKS) { VMCNT(4); } else { VMCNT(0); }
    __builtin_amdgcn_s_barrier();
    asm volatile("" ::: "memory");
    if (ks + 2 < NKS) STAGE((ks + 2) % 3, ks + 2);

    const char* sA = smem + cur * 16384;
    const char* sB = sA + 8192;
    bf16x8 af[4], bfr[4];
#pragma unroll
    for (int i = 0; i < 4; i++)
      af[i] = *reinterpret_cast<const bf16x8*>(sA + (wr + i * 16 + cl) * 64 + kxl);
#pragma unroll
    for (int j = 0; j < 4; j++)
      bfr[j] = *reinterpret_cast<const bf16x8*>(sB + (wc + j * 16 + cl) * 64 + kxl);
#pragma unroll
    for (int i = 0; i < 4; i++)
#pragma unroll
      for (int j = 0; j < 4; j++)
        acc[i][j] = __builtin_amdgcn_mfma_f32_16x16x32_bf16(af[i], bfr[j], acc[i][j], 0, 0, 0);
  }
#undef STAGE

  // Epilogue: e = exp(s - C) with diagonal masked.
  // C-frag layout: col = cl, row = q*4 + r (within 16x16 frag (i,j)).
  const bool diagw = (rt == ct) && (wr == wc);
  float psum[4][4];
#pragma unroll
  for (int i = 0; i < 4; i++)
#pragma unroll
    for (int r = 0; r < 4; r++) psum[i][r] = 0.f;
  float colp[4] = {0.f, 0.f, 0.f, 0.f};

#pragma unroll
  for (int i = 0; i < 4; i++)
#pragma unroll
    for (int j = 0; j < 4; j++)
#pragma unroll
      for (int r = 0; r < 4; r++) {
        float e = exp2f(fmaf(acc[i][j][r], LOG2E, -C_LOG2E));
        if (diagw && (i == j) && (cl == q * 4 + r)) e = 0.f;
        psum[i][r] += e;
        colp[j] += e;
      }

  // row sums -> rt rows (reduce across cols: cl lanes)
#pragma unroll
  for (int i = 0; i < 4; i++)
#pragma unroll
    for (int r = 0; r < 4; r++) {
      float v = psum[i][r];
      v += __shfl_xor(v, 1, 64);
      v += __shfl_xor(v, 2, 64);
      v += __shfl_xor(v, 4, 64);
      v += __shfl_xor(v, 8, 64);
      if (cl == 0) atomicAdd(&rowsum[rt * 128 + wr + i * 16 + q * 4 + r], v);
    }

  // col sums -> ct rows (reduce across rows: q lanes), off-diagonal tiles only
  if (rt != ct) {
#pragma unroll
    for (int j = 0; j < 4; j++) {
      float v = colp[j];
      v += __shfl_xor(v, 16, 64);
      v += __shfl_xor(v, 32, 64);
      if (q == 0) atomicAdd(&rowsum[ct * 128 + wc + j * 16 + cl], v);
    }
  }
}

// Single-block finalize: 1024 threads, each handles 8 rows.
__global__ void k_final(const float* __restrict__ rowsum, const float* __restrict__ posbuf,
                        float* __restrict__ out) {
  __shared__ float red[16];
  const int t = threadIdx.x;   // 1024 threads
  float s = 0.f;
#pragma unroll
  for (int it = 0; it < TWO_N / 1024; it++) {
    const int row = it * 1024 + t;
    float v = logf(rowsum[row]);
    if (row < N_ROWS) v -= 2.f * posbuf[row];
    s += v;
  }
#pragma unroll
  for (int off = 32; off > 0; off >>= 1) s += __shfl_down(s, off, 64);
  if ((t & 63) == 0) red[t >> 6] = s;
  __syncthreads();
  if (t == 0) {
    float tot = 0.f;
#pragma unroll
    for (int i = 0; i < 16; i++) tot += red[i];
    out[0] = tot / (float)TWO_N + INV_T;
  }
}

extern "C" void kernel_launch(void* const* d_in, const int* in_sizes, int n_in,
                              void* d_out, int out_size, void* d_ws, size_t ws_size,
                              hipStream_t stream) {
  const float* z1 = (const float*)d_in[0];
  const float* z2 = (const float*)d_in[1];
  float* out = (float*)d_out;
  char* ws = (char*)d_ws;

  __hip_bfloat16* zn = (__hip_bfloat16*)ws;              // 8192*512*2 = 8388608 B
  float* rowsum = (float*)(ws + 8388608);                 // 8192*4 = 32768 B
  float* posbuf = (float*)(ws + 8421376);                 // 4096*4 = 16384 B

  k_prep<<<1024, 256, 0, stream>>>(z1, z2, zn, posbuf, rowsum);
  k_lse<<<2080, 256, 0, stream>>>(zn, rowsum);
  k_final<<<1, 1024, 0, stream>>>(rowsum, posbuf, out);
}

// Round 9
// 121.902 us; speedup vs baseline: 1.2115x; 1.0932x over previous
//
#include <hip/hip_runtime.h>
#include <hip/hip_bf16.h>
#include <hip/hip_fp8.h>

#define N_ROWS 4096
#define TWO_N 8192
#define DIM 512                             // elements per row; fp8 row = 512 B
#define BKB 64                              // K elems (=bytes) per iter in fp8
#define NKS (DIM / BKB)                     // 8 K-steps
#define INV_T 14.285714285714286f           // 1/0.07
#define LOG2E 1.4426950408889634f
#define C_LOG2E 20.60992915555662f          // (1/0.07)*log2(e)
#define INV_SQRT_T 3.7796447300922722f      // 1/sqrt(0.07)

typedef float f32x4 __attribute__((ext_vector_type(4)));
typedef long fp8x8;                          // 8 fp8 = 64-bit MFMA operand

#define ASYNC_COPY16(gp, lp)                                                     \
  __builtin_amdgcn_global_load_lds((const __attribute__((address_space(1))) void*)(gp), \
                                   (__attribute__((address_space(3))) void*)(lp), 16, 0, 0)

#define VMCNT(n) asm volatile("s_waitcnt vmcnt(" #n ")" ::: "memory")

// Wave-per-row prep: float4 loads, butterfly shuffle reduce, then pack
// zhat/sqrt(T) to fp8 e4m3 (8 B per lane). posbuf (the subtracted positive)
// stays FP32-EXACT, so fp8 error only enters through the LSE term.
__global__ __launch_bounds__(256) void k_prep(const float* __restrict__ z1,
                                              const float* __restrict__ z2,
                                              unsigned char* __restrict__ zn,
                                              float* __restrict__ posbuf,
                                              float* __restrict__ rowsum) {
  const int t = threadIdx.x;
  const int wv = t >> 6, lane = t & 63;
  const int r = blockIdx.x * 4 + wv;
  if (blockIdx.x < 32) rowsum[blockIdx.x * 256 + t] = 0.f;   // 32*256 = 8192

  const float4* p1 = reinterpret_cast<const float4*>(z1 + (size_t)r * DIM) + (lane << 1);
  const float4* p2 = reinterpret_cast<const float4*>(z2 + (size_t)r * DIM) + (lane << 1);
  float4 a0 = p1[0], a1 = p1[1];
  float4 b0 = p2[0], b1 = p2[1];

  float s1 = a0.x * a0.x + a0.y * a0.y + a0.z * a0.z + a0.w * a0.w
           + a1.x * a1.x + a1.y * a1.y + a1.z * a1.z + a1.w * a1.w;
  float s2 = b0.x * b0.x + b0.y * b0.y + b0.z * b0.z + b0.w * b0.w
           + b1.x * b1.x + b1.y * b1.y + b1.z * b1.z + b1.w * b1.w;
  float sd = a0.x * b0.x + a0.y * b0.y + a0.z * b0.z + a0.w * b0.w
           + a1.x * b1.x + a1.y * b1.y + a1.z * b1.z + a1.w * b1.w;
#pragma unroll
  for (int off = 1; off < 64; off <<= 1) {
    s1 += __shfl_xor(s1, off, 64);
    s2 += __shfl_xor(s2, off, 64);
    sd += __shfl_xor(sd, off, 64);
  }
  const float sc1 = INV_SQRT_T / fmaxf(sqrtf(s1), 1e-8f);
  const float sc2 = INV_SQRT_T / fmaxf(sqrtf(s2), 1e-8f);

  float va[8] = {a0.x, a0.y, a0.z, a0.w, a1.x, a1.y, a1.z, a1.w};
  float vb[8] = {b0.x, b0.y, b0.z, b0.w, b1.x, b1.y, b1.z, b1.w};
  unsigned long long pa = 0, pb = 0;
#pragma unroll
  for (int d = 0; d < 8; d++) {
    __hip_fp8_e4m3 qa(va[d] * sc1);
    __hip_fp8_e4m3 qb(vb[d] * sc2);
    pa |= (unsigned long long)qa.__x << (8 * d);
    pb |= (unsigned long long)qb.__x << (8 * d);
  }
  *reinterpret_cast<unsigned long long*>(zn + (size_t)r * DIM + lane * 8) = pa;
  *reinterpret_cast<unsigned long long*>(zn + (size_t)(r + N_ROWS) * DIM + lane * 8) = pb;

  if (lane == 0) posbuf[r] = sd * sc1 * sc2;   // fp32-exact cos(z1_r,z2_r)/T
}

// ---------------------------------------------------------------------------
// Flash-LSE GEMM over upper-triangle 128x128 tiles -- FP8 e4m3 edition.
// r8 post-mortem: the kernel is LDS-BANDWIDTH-bound (108 KB/CU-iter through
// the LDS pipe ~ 990cy of the measured 1246cy; 78% of the LDS roofline).
// fp8 halves every byte at the same MFMA FLOP rate: BK=64 in fp8 keeps the
// buffer at 16 KB (A 8K + B 8K), so the CHAMPION skeleton is unchanged:
// 3 buffers (48 KB -> 3 blocks/CU), counted VMCNT(4) (2-iter slack, 4 copies
// per thread per stage), raw s_barrier, XCD-bijective swizzle. 8 K-steps.
//
// fp8 LDS swizzle (both sides, rule #21): 16B granule g of row r stored at
// slot-granule g ^ key(r), key(r) = (r&3)^((r>>2)&3). Store side: LDS dest
// linear (slot=tid), GLOBAL source granule pre-swizzled (tid&3)^key(r0).
// Read side: lane (cl,q) reads 8B of logical granule (ksub*2 + (q>>1)) at
// slot granule ^ key(cl)=(cl&3)^(cl>>2), byte (q&1)*8. Bank audit: each
// b64 wave-read hits every bank exactly 4x = the 512B/wave floor.
// Frag k-mapping (16x16x32, 8 elems/lane): lane q holds k = q*8..q*8+7,
// same geometry as the validated bf16 16x16x32 path.
// ---------------------------------------------------------------------------
__global__ __launch_bounds__(256, 3) void k_lse(const unsigned char* __restrict__ Zn,
                                                float* __restrict__ rowsum) {
  __shared__ char smem[49152] __attribute__((aligned(16)));
  const int tid  = threadIdx.x;
  const int wave = tid >> 6;
  const int lane = tid & 63;
  const int cl   = lane & 15;
  const int q    = lane >> 4;

  // XCD-aware bijective swizzle: 2080 = 8 * 260.
  const int b = (blockIdx.x & 7) * 260 + (blockIdx.x >> 3);

  // linear tile -> (rt, ct) with rt <= ct over 64x64 tile grid
  int rt = (int)((129.0f - sqrtf(16641.0f - 8.0f * (float)b)) * 0.5f);
  if (rt > 63) rt = 63;
  if (rt < 0) rt = 0;
  while (rt > 0 && 64 * rt - rt * (rt - 1) / 2 > b) rt--;
  while (64 * (rt + 1) - (rt + 1) * rt / 2 <= b) rt++;
  const int ct = rt + (b - (64 * rt - rt * (rt - 1) / 2));

  const int wr = (wave >> 1) * 64;   // wave's row offset in tile
  const int wc = (wave & 1) * 64;    // wave's col offset in tile

  // staging: thread owns slots tid, tid+256 of each 128x64B tile (512 granules)
  const int r0  = tid >> 2;                                   // 0..63
  const int kg0 = ((tid & 3) ^ (r0 & 3) ^ ((r0 >> 2) & 3)) * 16;  // pre-swizzled granule byte
  const unsigned char* gA0 = Zn + (size_t)(rt * 128 + r0) * DIM + kg0;
  const unsigned char* gB0 = Zn + (size_t)(ct * 128 + r0) * DIM + kg0;

  f32x4 acc[4][4] = {};
  // read-side lane constants
  const int xk = (cl & 3) ^ (cl >> 2);   // = key(row) for all rows this lane reads
  const int qh = q >> 1;                 // granule half-select
  const int qb = (q & 1) * 8;            // byte offset within granule

#define STAGE(d, it)                                                        \
  {                                                                         \
    char* _b = smem + (d) * 16384 + wave * 1024;                            \
    const int _ko = (it) * BKB;                                             \
    ASYNC_COPY16(gA0 + _ko,            _b);                                 \
    ASYNC_COPY16(gA0 + _ko + 64 * DIM, _b + 4096);                          \
    ASYNC_COPY16(gB0 + _ko,            _b + 8192);                          \
    ASYNC_COPY16(gB0 + _ko + 64 * DIM, _b + 12288);                         \
  }

  STAGE(0, 0);
  STAGE(1, 1);
#pragma unroll
  for (int ks = 0; ks < NKS; ks++) {
    const int cur = ks % 3;
    // wait for buf[cur]'s 4 loads (issued 2 iterations ago); the newest 4
    // (next buffer) stay in flight. Full drain only on the last iteration.
    if (ks + 1 < NKS) { VMCNT(4); } else { VMCNT(0); }
    __builtin_amdgcn_s_barrier();
    asm volatile("" ::: "memory");
    if (ks + 2 < NKS) STAGE((ks + 2) % 3, ks + 2);

    const char* sA = smem + cur * 16384;
    const char* sB = sA + 8192;
    fp8x8 af[2][4], bfr[2][4];
#pragma unroll
    for (int ksub = 0; ksub < 2; ksub++) {
      const int gsl = (((ksub << 1) | qh) ^ xk) * 16 + qb;
#pragma unroll
      for (int i = 0; i < 4; i++)
        af[ksub][i] = *reinterpret_cast<const fp8x8*>(sA + (wr + i * 16 + cl) * 64 + gsl);
#pragma unroll
      for (int j = 0; j < 4; j++)
        bfr[ksub][j] = *reinterpret_cast<const fp8x8*>(sB + (wc + j * 16 + cl) * 64 + gsl);
    }
#pragma unroll
    for (int ksub = 0; ksub < 2; ksub++)
#pragma unroll
      for (int i = 0; i < 4; i++)
#pragma unroll
        for (int j = 0; j < 4; j++)
          acc[i][j] = __builtin_amdgcn_mfma_f32_16x16x32_fp8_fp8(af[ksub][i], bfr[ksub][j],
                                                                 acc[i][j], 0, 0, 0);
  }
#undef STAGE

  // Epilogue: e = exp(s - C) with diagonal masked.
  // C-frag layout: col = cl, row = q*4 + r (dtype-independent on gfx950).
  const bool diagw = (rt == ct) && (wr == wc);
  float psum[4][4];
#pragma unroll
  for (int i = 0; i < 4; i++)
#pragma unroll
    for (int r = 0; r < 4; r++) psum[i][r] = 0.f;
  float colp[4] = {0.f, 0.f, 0.f, 0.f};

#pragma unroll
  for (int i = 0; i < 4; i++)
#pragma unroll
    for (int j = 0; j < 4; j++)
#pragma unroll
      for (int r = 0; r < 4; r++) {
        float e = exp2f(fmaf(acc[i][j][r], LOG2E, -C_LOG2E));
        if (diagw && (i == j) && (cl == q * 4 + r)) e = 0.f;
        psum[i][r] += e;
        colp[j] += e;
      }

  // row sums -> rt rows (reduce across cols: cl lanes)
#pragma unroll
  for (int i = 0; i < 4; i++)
#pragma unroll
    for (int r = 0; r < 4; r++) {
      float v = psum[i][r];
      v += __shfl_xor(v, 1, 64);
      v += __shfl_xor(v, 2, 64);
      v += __shfl_xor(v, 4, 64);
      v += __shfl_xor(v, 8, 64);
      if (cl == 0) atomicAdd(&rowsum[rt * 128 + wr + i * 16 + q * 4 + r], v);
    }

  // col sums -> ct rows (reduce across rows: q lanes), off-diagonal tiles only
  if (rt != ct) {
#pragma unroll
    for (int j = 0; j < 4; j++) {
      float v = colp[j];
      v += __shfl_xor(v, 16, 64);
      v += __shfl_xor(v, 32, 64);
      if (q == 0) atomicAdd(&rowsum[ct * 128 + wc + j * 16 + cl], v);
    }
  }
}

// Single-block finalize: 1024 threads, each handles 8 rows.
__global__ void k_final(const float* __restrict__ rowsum, const float* __restrict__ posbuf,
                        float* __restrict__ out) {
  __shared__ float red[16];
  const int t = threadIdx.x;   // 1024 threads
  float s = 0.f;
#pragma unroll
  for (int it = 0; it < TWO_N / 1024; it++) {
    const int row = it * 1024 + t;
    float v = logf(rowsum[row]);
    if (row < N_ROWS) v -= 2.f * posbuf[row];
    s += v;
  }
#pragma unroll
  for (int off = 32; off > 0; off >>= 1) s += __shfl_down(s, off, 64);
  if ((t & 63) == 0) red[t >> 6] = s;
  __syncthreads();
  if (t == 0) {
    float tot = 0.f;
#pragma unroll
    for (int i = 0; i < 16; i++) tot += red[i];
    out[0] = tot / (float)TWO_N + INV_T;
  }
}

extern "C" void kernel_launch(void* const* d_in, const int* in_sizes, int n_in,
                              void* d_out, int out_size, void* d_ws, size_t ws_size,
                              hipStream_t stream) {
  const float* z1 = (const float*)d_in[0];
  const float* z2 = (const float*)d_in[1];
  float* out = (float*)d_out;
  char* ws = (char*)d_ws;

  unsigned char* zn = (unsigned char*)ws;                 // 8192*512*1 = 4194304 B
  float* rowsum = (float*)(ws + 4194304);                 // 8192*4 = 32768 B
  float* posbuf = (float*)(ws + 4227072);                 // 4096*4 = 16384 B

  k_prep<<<1024, 256, 0, stream>>>(z1, z2, zn, posbuf, rowsum);
  k_lse<<<2080, 256, 0, stream>>>(zn, rowsum);
  k_final<<<1, 1024, 0, stream>>>(rowsum, posbuf, out);
}

// Round 10
// 117.867 us; speedup vs baseline: 1.2530x; 1.0342x over previous
//
#include <hip/hip_runtime.h>
#include <hip/hip_bf16.h>
#include <hip/hip_fp8.h>

#define N_ROWS 4096
#define TWO_N 8192
#define DIM 512                             // elements per row; fp8 row = 512 B
#define BKB 64                              // K bytes per iter in fp8
#define NKS (DIM / BKB)                     // 8 K-steps
#define INV_T 14.285714285714286f           // 1/0.07
#define LOG2E 1.4426950408889634f
#define C_LOG2E 20.60992915555662f          // (1/0.07)*log2(e)
#define INV_SQRT_T 3.7796447300922722f      // 1/sqrt(0.07)

typedef float f32x4 __attribute__((ext_vector_type(4)));
typedef long fp8x8;                          // 8 fp8 = one 64-bit MFMA operand
typedef long fp8x8x2 __attribute__((ext_vector_type(2)));   // b128 = 2 operands

#define ASYNC_COPY16(gp, lp)                                                     \
  __builtin_amdgcn_global_load_lds((const __attribute__((address_space(1))) void*)(gp), \
                                   (__attribute__((address_space(3))) void*)(lp), 16, 0, 0)

#define VMCNT(n) asm volatile("s_waitcnt vmcnt(" #n ")" ::: "memory")

// Wave-per-row prep: float4 loads, butterfly shuffle reduce, fp8 e4m3 pack.
// Zn is stored K-PERMUTED: within each 64B k-block, 8B slot l (k=l*8..l*8+7)
// is placed at position (l&3)*16 + (l>>2)*8, i.e. order [0,4,1,5,2,6,3,7].
// This makes the two operands MFMA-lane q needs (slots q, q+4) ADJACENT, so
// k_lse reads one b128 per fragment pair. Exact: a global k-permutation of
// the Gram matrix's inner dim, applied identically to A and B.
// posbuf (the subtracted positive) stays FP32-exact.
__global__ __launch_bounds__(256) void k_prep(const float* __restrict__ z1,
                                              const float* __restrict__ z2,
                                              unsigned char* __restrict__ zn,
                                              float* __restrict__ posbuf,
                                              float* __restrict__ rowsum) {
  const int t = threadIdx.x;
  const int wv = t >> 6, lane = t & 63;
  const int r = blockIdx.x * 4 + wv;
  if (blockIdx.x < 32) rowsum[blockIdx.x * 256 + t] = 0.f;   // 32*256 = 8192

  const float4* p1 = reinterpret_cast<const float4*>(z1 + (size_t)r * DIM) + (lane << 1);
  const float4* p2 = reinterpret_cast<const float4*>(z2 + (size_t)r * DIM) + (lane << 1);
  float4 a0 = p1[0], a1 = p1[1];
  float4 b0 = p2[0], b1 = p2[1];

  float s1 = a0.x * a0.x + a0.y * a0.y + a0.z * a0.z + a0.w * a0.w
           + a1.x * a1.x + a1.y * a1.y + a1.z * a1.z + a1.w * a1.w;
  float s2 = b0.x * b0.x + b0.y * b0.y + b0.z * b0.z + b0.w * b0.w
           + b1.x * b1.x + b1.y * b1.y + b1.z * b1.z + b1.w * b1.w;
  float sd = a0.x * b0.x + a0.y * b0.y + a0.z * b0.z + a0.w * b0.w
           + a1.x * b1.x + a1.y * b1.y + a1.z * b1.z + a1.w * b1.w;
#pragma unroll
  for (int off = 1; off < 64; off <<= 1) {
    s1 += __shfl_xor(s1, off, 64);
    s2 += __shfl_xor(s2, off, 64);
    sd += __shfl_xor(sd, off, 64);
  }
  const float sc1 = INV_SQRT_T / fmaxf(sqrtf(s1), 1e-8f);
  const float sc2 = INV_SQRT_T / fmaxf(sqrtf(s2), 1e-8f);

  float va[8] = {a0.x, a0.y, a0.z, a0.w, a1.x, a1.y, a1.z, a1.w};
  float vb[8] = {b0.x, b0.y, b0.z, b0.w, b1.x, b1.y, b1.z, b1.w};
  unsigned long long pa = 0, pb = 0;
#pragma unroll
  for (int d = 0; d < 8; d++) {
    __hip_fp8_e4m3 qa(va[d] * sc1);
    __hip_fp8_e4m3 qb(vb[d] * sc2);
    pa |= (unsigned long long)qa.__x << (8 * d);
    pb |= (unsigned long long)qb.__x << (8 * d);
  }
  // lane covers k = lane*8..+7 -> block = lane>>3, slot l = lane&7,
  // permuted position = block*64 + (l&3)*16 + (l>>2)*8
  const int pofs = (lane >> 3) * 64 + (lane & 3) * 16 + ((lane >> 2) & 1) * 8;
  *reinterpret_cast<unsigned long long*>(zn + (size_t)r * DIM + pofs) = pa;
  *reinterpret_cast<unsigned long long*>(zn + (size_t)(r + N_ROWS) * DIM + pofs) = pb;

  if (lane == 0) posbuf[r] = sd * sc1 * sc2;   // fp32-exact cos(z1_r,z2_r)/T
}

// ---------------------------------------------------------------------------
// Flash-LSE GEMM over upper-triangle 128x128 tiles -- FP8 e4m3, b128 reads.
// r9 post-mortem: the b64 read swizzle was 2-way-conflicted on EVERY read
// (row stride 64B leaves only cl&1 + 2 granule bits = 3 bank-select bits for
// a 16-lane phase) -> 4.26M conflict cycles, and 16 reads/iter doubled
// instruction count. Fix: K-PERMUTED global layout (see k_prep) makes the
// (ksub=0, ksub=1) operand pair contiguous -> 8x ds_read_b128 per iter, and
// the bank-quad audit for 8-lane b128 phases gives (cl&1)*4 + (q^((cl>>1)&3))
// = all 8 quads exactly once -> conflict-free.
//
// CHAMPION skeleton unchanged (r2/r9): 3 LDS buffers 48KB -> 3 blocks/CU,
// counted VMCNT(4) (2-iter slack, full drain only at tail), raw s_barrier,
// stage-after-barrier, XCD-bijective block swizzle. 8 K-steps.
//
// Swizzle (rule #21, both sides): LDS granule (row*4 + s) holds position-
// granule s ^ key(row), key = (row>>1)&3. Store: LDS dest linear (slot=tid),
// GLOBAL source granule pre-swizzled (tid&3)^key(r0) (key equal for r0 and
// r0+64). Read: lane (cl,q) -> addr = row*64 + ((q ^ ((cl>>1)&3))<<4); low
// 8B = ksub0 operand, high 8B = ksub1.
// ---------------------------------------------------------------------------
__global__ __launch_bounds__(256, 3) void k_lse(const unsigned char* __restrict__ Zn,
                                                float* __restrict__ rowsum) {
  __shared__ char smem[49152] __attribute__((aligned(16)));
  const int tid  = threadIdx.x;
  const int wave = tid >> 6;
  const int lane = tid & 63;
  const int cl   = lane & 15;
  const int q    = lane >> 4;

  // XCD-aware bijective swizzle: 2080 = 8 * 260.
  const int b = (blockIdx.x & 7) * 260 + (blockIdx.x >> 3);

  // linear tile -> (rt, ct) with rt <= ct over 64x64 tile grid
  int rt = (int)((129.0f - sqrtf(16641.0f - 8.0f * (float)b)) * 0.5f);
  if (rt > 63) rt = 63;
  if (rt < 0) rt = 0;
  while (rt > 0 && 64 * rt - rt * (rt - 1) / 2 > b) rt--;
  while (64 * (rt + 1) - (rt + 1) * rt / 2 <= b) rt++;
  const int ct = rt + (b - (64 * rt - rt * (rt - 1) / 2));

  const int wr = (wave >> 1) * 64;   // wave's row offset in tile
  const int wc = (wave & 1) * 64;    // wave's col offset in tile

  // staging: thread owns granules tid, tid+256 of each 128x64B tile
  const int r0  = tid >> 2;                              // 0..63
  const int sg  = ((tid & 3) ^ ((r0 >> 1) & 3)) * 16;    // pre-swizzled granule byte
  const unsigned char* gA0 = Zn + (size_t)(rt * 128 + r0) * DIM + sg;
  const unsigned char* gB0 = Zn + (size_t)(ct * 128 + r0) * DIM + sg;

  f32x4 acc[4][4] = {};
  const int xk2 = (cl >> 1) & 3;        // read-side key (row bits from cl)
  const int gofs = ((q ^ xk2) << 4);    // granule byte offset within row

#define STAGE(d, it)                                                        \
  {                                                                         \
    char* _b = smem + (d) * 16384 + wave * 1024;                            \
    const int _ko = (it) * BKB;                                             \
    ASYNC_COPY16(gA0 + _ko,            _b);                                 \
    ASYNC_COPY16(gA0 + _ko + 64 * DIM, _b + 4096);                          \
    ASYNC_COPY16(gB0 + _ko,            _b + 8192);                          \
    ASYNC_COPY16(gB0 + _ko + 64 * DIM, _b + 12288);                         \
  }

  STAGE(0, 0);
  STAGE(1, 1);
#pragma unroll
  for (int ks = 0; ks < NKS; ks++) {
    const int cur = ks % 3;
    // wait for buf[cur]'s 4 loads (issued 2 iterations ago); the newest 4
    // (next buffer) stay in flight. Full drain only on the last iteration.
    if (ks + 1 < NKS) { VMCNT(4); } else { VMCNT(0); }
    __builtin_amdgcn_s_barrier();
    asm volatile("" ::: "memory");
    if (ks + 2 < NKS) STAGE((ks + 2) % 3, ks + 2);

    const char* sA = smem + cur * 16384;
    const char* sB = sA + 8192;
    fp8x8 af[2][4], bfr[2][4];
#pragma unroll
    for (int i = 0; i < 4; i++) {
      fp8x8x2 av = *reinterpret_cast<const fp8x8x2*>(sA + (wr + i * 16 + cl) * 64 + gofs);
      af[0][i] = av[0];
      af[1][i] = av[1];
    }
#pragma unroll
    for (int j = 0; j < 4; j++) {
      fp8x8x2 bv = *reinterpret_cast<const fp8x8x2*>(sB + (wc + j * 16 + cl) * 64 + gofs);
      bfr[0][j] = bv[0];
      bfr[1][j] = bv[1];
    }
#pragma unroll
    for (int ksub = 0; ksub < 2; ksub++)
#pragma unroll
      for (int i = 0; i < 4; i++)
#pragma unroll
        for (int j = 0; j < 4; j++)
          acc[i][j] = __builtin_amdgcn_mfma_f32_16x16x32_fp8_fp8(af[ksub][i], bfr[ksub][j],
                                                                 acc[i][j], 0, 0, 0);
  }
#undef STAGE

  // Epilogue: e = exp(s - C) with diagonal masked.
  // C-frag layout: col = cl, row = q*4 + r (dtype-independent on gfx950).
  const bool diagw = (rt == ct) && (wr == wc);
  float psum[4][4];
#pragma unroll
  for (int i = 0; i < 4; i++)
#pragma unroll
    for (int r = 0; r < 4; r++) psum[i][r] = 0.f;
  float colp[4] = {0.f, 0.f, 0.f, 0.f};

#pragma unroll
  for (int i = 0; i < 4; i++)
#pragma unroll
    for (int j = 0; j < 4; j++)
#pragma unroll
      for (int r = 0; r < 4; r++) {
        float e = exp2f(fmaf(acc[i][j][r], LOG2E, -C_LOG2E));
        if (diagw && (i == j) && (cl == q * 4 + r)) e = 0.f;
        psum[i][r] += e;
        colp[j] += e;
      }

  // row sums -> rt rows (reduce across cols: cl lanes)
#pragma unroll
  for (int i = 0; i < 4; i++)
#pragma unroll
    for (int r = 0; r < 4; r++) {
      float v = psum[i][r];
      v += __shfl_xor(v, 1, 64);
      v += __shfl_xor(v, 2, 64);
      v += __shfl_xor(v, 4, 64);
      v += __shfl_xor(v, 8, 64);
      if (cl == 0) atomicAdd(&rowsum[rt * 128 + wr + i * 16 + q * 4 + r], v);
    }

  // col sums -> ct rows (reduce across rows: q lanes), off-diagonal tiles only
  if (rt != ct) {
#pragma unroll
    for (int j = 0; j < 4; j++) {
      float v = colp[j];
      v += __shfl_xor(v, 16, 64);
      v += __shfl_xor(v, 32, 64);
      if (q == 0) atomicAdd(&rowsum[ct * 128 + wc + j * 16 + cl], v);
    }
  }
}

// Single-block finalize: 1024 threads, each handles 8 rows.
__global__ void k_final(const float* __restrict__ rowsum, const float* __restrict__ posbuf,
                        float* __restrict__ out) {
  __shared__ float red[16];
  const int t = threadIdx.x;   // 1024 threads
  float s = 0.f;
#pragma unroll
  for (int it = 0; it < TWO_N / 1024; it++) {
    const int row = it * 1024 + t;
    float v = logf(rowsum[row]);
    if (row < N_ROWS) v -= 2.f * posbuf[row];
    s += v;
  }
#pragma unroll
  for (int off = 32; off > 0; off >>= 1) s += __shfl_down(s, off, 64);
  if ((t & 63) == 0) red[t >> 6] = s;
  __syncthreads();
  if (t == 0) {
    float tot = 0.f;
#pragma unroll
    for (int i = 0; i < 16; i++) tot += red[i];
    out[0] = tot / (float)TWO_N + INV_T;
  }
}

extern "C" void kernel_launch(void* const* d_in, const int* in_sizes, int n_in,
                              void* d_out, int out_size, void* d_ws, size_t ws_size,
                              hipStream_t stream) {
  const float* z1 = (const float*)d_in[0];
  const float* z2 = (const float*)d_in[1];
  float* out = (float*)d_out;
  char* ws = (char*)d_ws;

  unsigned char* zn = (unsigned char*)ws;                 // 8192*512*1 = 4194304 B
  float* rowsum = (float*)(ws + 4194304);                 // 8192*4 = 32768 B
  float* posbuf = (float*)(ws + 4227072);                 // 4096*4 = 16384 B

  k_prep<<<1024, 256, 0, stream>>>(z1, z2, zn, posbuf, rowsum);
  k_lse<<<2080, 256, 0, stream>>>(zn, rowsum);
  k_final<<<1, 1024, 0, stream>>>(rowsum, posbuf, out);
}